// Round 3
// baseline (3488.831 us; speedup 1.0000x reference)
//
#include <hip/hip_runtime.h>
#include <hip/hip_bf16.h>

#define HS 4096
#define NE 64
constexpr int KCH = 32;       // k-depth per staged chunk
constexpr int T   = 16;       // tokens per wave
constexpr int NW  = 4;        // waves per block
constexpr int TPB = NW * T;   // 64 tokens per block

// Kernel 1: partial logits. Grid (n_tokens/TPB, ksplit), block 256.
// lane = expert. Double-buffered LDS chunks: W (swizzled) + x (read as
// 64-lane broadcast ds_read_b128 -> vector path, not the 0.5 TB/s scalar path).
__global__ __launch_bounds__(256, 4)
void router_partial(const float* __restrict__ x, const float* __restrict__ W,
                    float* __restrict__ ws, int n_tokens, int k_per_split)
{
    __shared__ float4 smW[2][NE * KCH / 4];    // 2 x 8 KiB, XOR-swizzled rows
    __shared__ float4 smX[2][TPB * KCH / 4];   // 2 x 8 KiB, linear

    const int tid    = threadIdx.x;
    const int lane   = tid & 63;
    const int wid    = __builtin_amdgcn_readfirstlane(tid >> 6);
    const int k0     = blockIdx.y * k_per_split;
    const int token0 = blockIdx.x * TPB;
    const int nch    = k_per_split / KCH;
    const int swz    = lane & 7;

    float acc[T];
    #pragma unroll
    for (int t = 0; t < T; ++t) acc[t] = 0.f;

    // staging: 512 float4 slots each for W and x; thread handles slots {tid, tid+256}
    // slot s -> row (expert or token) = s>>3, quad q = s&7 (128 B per row, coalesced)

    { // prologue: chunk 0 -> buf 0
        #pragma unroll
        for (int r = 0; r < 2; ++r) {
            const int s = tid + r * 256;
            const int e = s >> 3, q = s & 7;
            float4 wv = *reinterpret_cast<const float4*>(W + (size_t)e * HS + k0 + q * 4);
            float4 xv = *reinterpret_cast<const float4*>(x + (size_t)(token0 + e) * HS + k0 + q * 4);
            smW[0][e * 8 + (q ^ (e & 7))] = wv;   // swizzled write
            smX[0][s] = xv;                        // linear
        }
    }
    __syncthreads();

    for (int ch = 0; ch < nch; ++ch) {
        const int cur = ch & 1;
        const bool pf = (ch + 1 < nch);
        float4 wv[2], xv[2];
        if (pf) {  // T14: issue next-chunk global loads EARLY, write to LDS late
            const int kb = k0 + (ch + 1) * KCH;
            #pragma unroll
            for (int r = 0; r < 2; ++r) {
                const int s = tid + r * 256;
                const int e = s >> 3, q = s & 7;
                wv[r] = *reinterpret_cast<const float4*>(W + (size_t)e * HS + kb + q * 4);
                xv[r] = *reinterpret_cast<const float4*>(x + (size_t)(token0 + e) * HS + kb + q * 4);
            }
        }

        // compute: w_reg from swizzled LDS (conflict-free), x via broadcast reads
        float4 wr[8];
        #pragma unroll
        for (int q = 0; q < 8; ++q)
            wr[q] = smW[cur][lane * 8 + (q ^ swz)];

        #pragma unroll
        for (int t = 0; t < T; ++t) {
            float a = acc[t];
            #pragma unroll
            for (int q = 0; q < 8; ++q) {
                float4 xq = smX[cur][(wid * T + t) * 8 + q];   // uniform addr -> broadcast
                a = fmaf(xq.x, wr[q].x, a);
                a = fmaf(xq.y, wr[q].y, a);
                a = fmaf(xq.z, wr[q].z, a);
                a = fmaf(xq.w, wr[q].w, a);
            }
            acc[t] = a;
        }

        if (pf) {  // LDS writes after compute; loads have had ~1024 cy to land
            #pragma unroll
            for (int r = 0; r < 2; ++r) {
                const int s = tid + r * 256;
                const int e = s >> 3, q = s & 7;
                smW[cur ^ 1][e * 8 + (q ^ (e & 7))] = wv[r];
                smX[cur ^ 1][s] = xv[r];
            }
        }
        __syncthreads();
    }

    #pragma unroll
    for (int t = 0; t < T; ++t)
        ws[((size_t)blockIdx.y * n_tokens + token0 + wid * T + t) * NE + lane] = acc[t];
}

// Kernel 2: reduce k-splits + softmax + top-2. One wave per token, lane = expert.
__global__ __launch_bounds__(256)
void router_finish(const float* __restrict__ ws, float* __restrict__ out,
                   int n_tokens, int ksplit)
{
    const int lane  = threadIdx.x & 63;
    const int token = blockIdx.x * 4 + (threadIdx.x >> 6);
    if (token >= n_tokens) return;

    float v = 0.f;
    for (int s = 0; s < ksplit; ++s)
        v += ws[(size_t)s * n_tokens * NE + (size_t)token * NE + lane];

    float m1 = v;
    #pragma unroll
    for (int off = 32; off >= 1; off >>= 1) m1 = fmaxf(m1, __shfl_xor(m1, off));
    unsigned long long b1 = __ballot(v == m1);      // lowest-index tie-break
    int i1 = __ffsll(b1) - 1;

    const float NINF = __int_as_float(0xff800000);
    float vx = (lane == i1) ? NINF : v;
    float m2 = vx;
    #pragma unroll
    for (int off = 32; off >= 1; off >>= 1) m2 = fmaxf(m2, __shfl_xor(m2, off));
    unsigned long long b2 = __ballot(vx == m2);
    int i2 = __ffsll(b2) - 1;

    float s = __expf(v - m1);
    #pragma unroll
    for (int off = 32; off >= 1; off >>= 1) s += __shfl_xor(s, off);

    if (lane == 0) {
        float inv = 1.0f / s;
        out[(size_t)token * 2 + 0] = inv;
        out[(size_t)token * 2 + 1] = __expf(m2 - m1) * inv;
        out[(size_t)n_tokens * 2 + (size_t)token * 2 + 0] = (float)i1;
        out[(size_t)n_tokens * 2 + (size_t)token * 2 + 1] = (float)i2;
    }
}

extern "C" void kernel_launch(void* const* d_in, const int* in_sizes, int n_in,
                              void* d_out, int out_size, void* d_ws, size_t ws_size,
                              hipStream_t stream)
{
    const float* x = (const float*)d_in[0];
    const float* W = (const float*)d_in[1];
    float* out = (float*)d_out;
    float* ws  = (float*)d_ws;

    const int n_tokens = in_sizes[0] / HS;            // 8192
    int ksplit = 8;                                   // 16 MiB partials
    while (ksplit > 1 &&
           (size_t)ksplit * n_tokens * NE * sizeof(float) > ws_size)
        ksplit >>= 1;
    const int kps = HS / ksplit;                      // multiple of KCH for all ksplit

    dim3 grid1(n_tokens / TPB, ksplit);               // (128, 8) = 1024 blocks
    router_partial<<<grid1, 256, 0, stream>>>(x, W, ws, n_tokens, kps);

    dim3 grid2((n_tokens + 3) / 4);
    router_finish<<<grid2, 256, 0, stream>>>(ws, out, n_tokens, ksplit);
}

// Round 4
// 138.916 us; speedup vs baseline: 25.1147x; 25.1147x over previous
//
#include <hip/hip_runtime.h>
#include <hip/hip_bf16.h>
#include <stdint.h>

#define HS 4096
#define NE 64
constexpr int T      = 16;            // tokens per wave
constexpr int NWAVES = 16;            // waves per block (1024 threads)
constexpr int TPB    = NWAVES * T;    // 256 tokens per block
constexpr int KSL    = 256;           // k staged per W-slice (64 KiB LDS)
constexpr int KCH    = 16;            // x chunk depth (1 KiB per wave buffer)

typedef __attribute__((address_space(3))) uint32_t lds_t;
typedef const __attribute__((address_space(1))) uint32_t glb_t;

// Kernel 1: partial logits. Grid (n_tokens/TPB, ksplit), block 1024.
// lane = expert. W slice XOR-swizzled in LDS (reg-staged, once per KSL);
// x streamed via global_load_lds into PER-WAVE double buffers -> the chunk
// loop is barrier-free with counted vmcnt(1). No register arrays beyond acc.
__global__ __launch_bounds__(1024, 4)
void router_partial(const float* __restrict__ x, const float* __restrict__ W,
                    float* __restrict__ ws, int n_tokens, int k_per_split)
{
    __shared__ float4 smW[NE][KSL / 4];              // 64 KiB, swizzled
    __shared__ float4 smX[NWAVES][2][T * KCH / 4];   // 32 KiB, linear per wave

    const int tid    = threadIdx.x;
    const int lane   = tid & 63;
    const int wid    = __builtin_amdgcn_readfirstlane(tid >> 6);
    const int k0     = blockIdx.y * k_per_split;
    const int token0 = blockIdx.x * TPB;
    const int swz    = lane & 31;

    float acc[T];
    #pragma unroll
    for (int t = 0; t < T; ++t) acc[t] = 0.f;

    // per-lane x source: token = wid*T + (lane>>2), k-quad = lane&3
    const float* xsrc = x + (size_t)(token0 + wid * T + (lane >> 2)) * HS
                          + k0 + (lane & 3) * 4;

    const int e  = tid >> 4;     // W staging: row 0..63
    const int sh = tid & 15;     // 16 float4 slots per round, 4 rounds

    #pragma unroll 1
    for (int ks = 0; ks < k_per_split; ks += KSL) {
        // prologue x load for this slice (per-wave buffer 0) -- overlaps staging
        __builtin_amdgcn_global_load_lds((glb_t*)(xsrc + ks),
                                         (lds_t*)&smX[wid][0][0], 16, 0, 0);
        if (ks) __syncthreads();             // all waves done reading smW
        #pragma unroll
        for (int r = 0; r < KSL / 4 / 16; ++r) {       // 4 rounds
            int slot = r * 16 + sh;                    // 0..63
            float4 wv = *reinterpret_cast<const float4*>(
                &W[(size_t)e * HS + k0 + ks + slot * 4]);
            smW[e][slot ^ (e & 31)] = wv;              // swizzled write
        }
        __syncthreads();

        constexpr int nch = KSL / KCH;                 // 16 chunks
        #pragma unroll 1
        for (int c = 0; c < nch; ++c) {
            if (c + 1 < nch) {                         // T4: counted, never 0
                __builtin_amdgcn_global_load_lds(
                    (glb_t*)(xsrc + ks + (c + 1) * KCH),
                    (lds_t*)&smX[wid][(c + 1) & 1][0], 16, 0, 0);
                asm volatile("s_waitcnt vmcnt(1)" ::: "memory");
            } else {
                asm volatile("s_waitcnt vmcnt(0)" ::: "memory");
            }
            __builtin_amdgcn_sched_barrier(0);

            const float4* xb = &smX[wid][c & 1][0];
            const int cq = c * 4;                      // quad base in slice
            float4 w0 = smW[lane][(cq + 0) ^ swz];     // bank-balanced reads
            float4 w1 = smW[lane][(cq + 1) ^ swz];
            float4 w2 = smW[lane][(cq + 2) ^ swz];
            float4 w3 = smW[lane][(cq + 3) ^ swz];
            #pragma unroll
            for (int t = 0; t < T; ++t) {
                float a = acc[t];
                float4 x0 = xb[t * 4 + 0];             // uniform addr: broadcast
                a = fmaf(x0.x, w0.x, a); a = fmaf(x0.y, w0.y, a);
                a = fmaf(x0.z, w0.z, a); a = fmaf(x0.w, w0.w, a);
                float4 x1 = xb[t * 4 + 1];
                a = fmaf(x1.x, w1.x, a); a = fmaf(x1.y, w1.y, a);
                a = fmaf(x1.z, w1.z, a); a = fmaf(x1.w, w1.w, a);
                float4 x2 = xb[t * 4 + 2];
                a = fmaf(x2.x, w2.x, a); a = fmaf(x2.y, w2.y, a);
                a = fmaf(x2.z, w2.z, a); a = fmaf(x2.w, w2.w, a);
                float4 x3 = xb[t * 4 + 3];
                a = fmaf(x3.x, w3.x, a); a = fmaf(x3.y, w3.y, a);
                a = fmaf(x3.z, w3.z, a); a = fmaf(x3.w, w3.w, a);
                acc[t] = a;
            }
        }
    }

    #pragma unroll
    for (int t = 0; t < T; ++t)
        ws[((size_t)blockIdx.y * n_tokens + token0 + wid * T + t) * NE + lane] = acc[t];
}

// Kernel 2: reduce k-splits + softmax + top-2. One wave per token, lane = expert.
__global__ __launch_bounds__(256)
void router_finish(const float* __restrict__ ws, float* __restrict__ out,
                   int n_tokens, int ksplit)
{
    const int lane  = threadIdx.x & 63;
    const int token = blockIdx.x * 4 + (threadIdx.x >> 6);
    if (token >= n_tokens) return;

    float v = 0.f;
    for (int s = 0; s < ksplit; ++s)
        v += ws[(size_t)s * n_tokens * NE + (size_t)token * NE + lane];

    float m1 = v;
    #pragma unroll
    for (int off = 32; off >= 1; off >>= 1) m1 = fmaxf(m1, __shfl_xor(m1, off));
    unsigned long long b1 = __ballot(v == m1);        // lowest-index tie-break
    int i1 = __ffsll(b1) - 1;

    const float NINF = __int_as_float(0xff800000);
    float vx = (lane == i1) ? NINF : v;
    float m2 = vx;
    #pragma unroll
    for (int off = 32; off >= 1; off >>= 1) m2 = fmaxf(m2, __shfl_xor(m2, off));
    unsigned long long b2 = __ballot(vx == m2);
    int i2 = __ffsll(b2) - 1;

    float s = __expf(v - m1);
    #pragma unroll
    for (int off = 32; off >= 1; off >>= 1) s += __shfl_xor(s, off);

    if (lane == 0) {
        float inv = 1.0f / s;
        out[(size_t)token * 2 + 0] = inv;
        out[(size_t)token * 2 + 1] = __expf(m2 - m1) * inv;
        out[(size_t)n_tokens * 2 + (size_t)token * 2 + 0] = (float)i1;
        out[(size_t)n_tokens * 2 + (size_t)token * 2 + 1] = (float)i2;
    }
}

extern "C" void kernel_launch(void* const* d_in, const int* in_sizes, int n_in,
                              void* d_out, int out_size, void* d_ws, size_t ws_size,
                              hipStream_t stream)
{
    const float* x = (const float*)d_in[0];
    const float* W = (const float*)d_in[1];
    float* out = (float*)d_out;
    float* ws  = (float*)d_ws;

    const int n_tokens = in_sizes[0] / HS;            // 8192
    int ksplit = 8;                                   // 16 MiB partials (proven fits)
    while (ksplit > 1 &&
           (size_t)ksplit * n_tokens * NE * sizeof(float) > ws_size)
        ksplit >>= 1;
    const int kps = HS / ksplit;                      // multiple of KSL for all ksplit

    dim3 grid1(n_tokens / TPB, ksplit);               // (32, 8) = 256 blocks, 1/CU
    router_partial<<<grid1, 1024, 0, stream>>>(x, W, ws, n_tokens, kps);

    dim3 grid2((n_tokens + 3) / 4);
    router_finish<<<grid2, 256, 0, stream>>>(ws, out, n_tokens, ksplit);
}

// Round 5
// 36.663 us; speedup vs baseline: 95.1586x; 3.7890x over previous
//
#include <hip/hip_runtime.h>
#include <hip/hip_bf16.h>
#include <stdint.h>

#define HS 4096
#define NE 64

using half8 = __attribute__((ext_vector_type(8))) _Float16;
using f32x4 = __attribute__((ext_vector_type(4))) float;

constexpr int KSPLIT = 8;
constexpr int KPS    = HS / KSPLIT;     // 512 k per split
constexpr int WPB    = 8;               // waves per block (512 threads)
constexpr int M_WAVE = 32;              // tokens per wave = 2 MFMA M-tiles
constexpr int M_BLK  = WPB * M_WAVE;    // 256 tokens per block

constexpr float XS = 16.f;              // x scale (keeps xl out of f16 denormals)
constexpr float WSC = 1024.f;           // W scale (keeps Wl out of f16 denormals)
constexpr float INV_SCALE = 1.f / (XS * WSC);   // 2^-14, applied in finish

// Fused: convert W k-slice fp32 -> f16 hi/lo planes in LDS, then MFMA GEMM.
// Grid (n_tokens/M_BLK, KSPLIT), block 512. Per wave: M=32 x N=64 x K=512.
__global__ __launch_bounds__(512, 1)
void router_gemm(const float* __restrict__ x, const float* __restrict__ W,
                 float* __restrict__ ws, int n_tokens)
{
    // slot layout: [(kg*2 + plane)*64 + expert] of half8 (16B), 128 KiB total
    __shared__ half8 Wl8[(KPS / 8) * 2 * NE];

    const int tid = threadIdx.x;
    const int l   = tid & 63;
    const int wv  = __builtin_amdgcn_readfirstlane(tid >> 6);
    const int g   = l >> 4;              // k-group 0..3
    const int e   = l & 15;              // row/col within tile
    const int k0  = blockIdx.y * KPS;

    // ---- stage W slice: fp32 -> scaled f16 hi/lo (once per block) ----
    {
        const int se = tid >> 3;         // expert row 0..63
        const int sc = tid & 7;          // 8-float chunk within 64-float stripe
        #pragma unroll
        for (int j = 0; j < 8; ++j) {
            const float* wp = W + (size_t)se * HS + k0 + sc * 8 + j * 64;
            float4 u = *reinterpret_cast<const float4*>(wp);
            float4 v = *reinterpret_cast<const float4*>(wp + 4);
            const int kg = sc + j * 8;
            float f[8] = {u.x, u.y, u.z, u.w, v.x, v.y, v.z, v.w};
            half8 h, lo;
            #pragma unroll
            for (int i = 0; i < 8; ++i) {
                float s = f[i] * WSC;
                _Float16 hh = (_Float16)s;
                h[i]  = hh;
                lo[i] = (_Float16)(s - (float)hh);
            }
            Wl8[(kg * 2 + 0) * NE + se] = h;
            Wl8[(kg * 2 + 1) * NE + se] = lo;
        }
    }
    __syncthreads();

    // ---- barrier-free MFMA k-loop ----
    const int m0 = blockIdx.x * M_BLK + wv * M_WAVE;
    const float* xr0 = x + (size_t)(m0 + e) * HS + k0 + g * 8;   // M-tile 0
    const float* xr1 = xr0 + (size_t)16 * HS;                    // M-tile 1

    f32x4 acc[2][4];
    #pragma unroll
    for (int i = 0; i < 2; ++i)
        #pragma unroll
        for (int j = 0; j < 4; ++j) acc[i][j] = (f32x4){0.f, 0.f, 0.f, 0.f};

    float4 c00 = *reinterpret_cast<const float4*>(xr0);
    float4 c01 = *reinterpret_cast<const float4*>(xr0 + 4);
    float4 c10 = *reinterpret_cast<const float4*>(xr1);
    float4 c11 = *reinterpret_cast<const float4*>(xr1 + 4);

    #pragma unroll 2
    for (int ks = 0; ks < KPS / 32; ++ks) {
        float4 n00 = c00, n01 = c01, n10 = c10, n11 = c11;
        if (ks + 1 < KPS / 32) {                 // prefetch next k-step's x
            const float* p0 = xr0 + (ks + 1) * 32;
            const float* p1 = xr1 + (ks + 1) * 32;
            n00 = *reinterpret_cast<const float4*>(p0);
            n01 = *reinterpret_cast<const float4*>(p0 + 4);
            n10 = *reinterpret_cast<const float4*>(p1);
            n11 = *reinterpret_cast<const float4*>(p1 + 4);
        }

        // B fragments from LDS (hi/lo planes), same (g,j)->k map as A
        const int sb = (ks * 4 + g) * 2;
        half8 bh[4], bl[4];
        #pragma unroll
        for (int nt = 0; nt < 4; ++nt) {
            bh[nt] = Wl8[(sb + 0) * NE + nt * 16 + e];
            bl[nt] = Wl8[(sb + 1) * NE + nt * 16 + e];
        }

        // A fragments: fp32 -> scaled f16 hi/lo
        half8 ah0, al0, ah1, al1;
        {
            float f0[8] = {c00.x, c00.y, c00.z, c00.w, c01.x, c01.y, c01.z, c01.w};
            float f1[8] = {c10.x, c10.y, c10.z, c10.w, c11.x, c11.y, c11.z, c11.w};
            #pragma unroll
            for (int i = 0; i < 8; ++i) {
                float s0 = f0[i] * XS; _Float16 h0 = (_Float16)s0;
                ah0[i] = h0; al0[i] = (_Float16)(s0 - (float)h0);
                float s1 = f1[i] * XS; _Float16 h1 = (_Float16)s1;
                ah1[i] = h1; al1[i] = (_Float16)(s1 - (float)h1);
            }
        }

        // 3-term split-f16 accumulation: xh*Wh + xl*Wh + xh*Wl
        #pragma unroll
        for (int nt = 0; nt < 4; ++nt) {
            acc[0][nt] = __builtin_amdgcn_mfma_f32_16x16x32_f16(ah0, bh[nt], acc[0][nt], 0, 0, 0);
            acc[0][nt] = __builtin_amdgcn_mfma_f32_16x16x32_f16(al0, bh[nt], acc[0][nt], 0, 0, 0);
            acc[0][nt] = __builtin_amdgcn_mfma_f32_16x16x32_f16(ah0, bl[nt], acc[0][nt], 0, 0, 0);
            acc[1][nt] = __builtin_amdgcn_mfma_f32_16x16x32_f16(ah1, bh[nt], acc[1][nt], 0, 0, 0);
            acc[1][nt] = __builtin_amdgcn_mfma_f32_16x16x32_f16(al1, bh[nt], acc[1][nt], 0, 0, 0);
            acc[1][nt] = __builtin_amdgcn_mfma_f32_16x16x32_f16(ah1, bl[nt], acc[1][nt], 0, 0, 0);
        }

        c00 = n00; c01 = n01; c10 = n10; c11 = n11;
    }

    // ---- epilogue: C layout col=lane&15 (expert), row=(lane>>4)*4+reg (token) ----
    #pragma unroll
    for (int mt = 0; mt < 2; ++mt)
        #pragma unroll
        for (int nt = 0; nt < 4; ++nt)
            #pragma unroll
            for (int r = 0; r < 4; ++r) {
                const int tok = m0 + mt * 16 + g * 4 + r;
                const int ex  = nt * 16 + e;
                ws[((size_t)blockIdx.y * n_tokens + tok) * NE + ex] = acc[mt][nt][r];
            }
}

// Finish: reduce k-splits, unscale, softmax, top-2. One wave per token.
__global__ __launch_bounds__(256)
void router_finish(const float* __restrict__ ws, float* __restrict__ out,
                   int n_tokens)
{
    const int lane  = threadIdx.x & 63;
    const int token = blockIdx.x * 4 + (threadIdx.x >> 6);
    if (token >= n_tokens) return;

    float v = 0.f;
    #pragma unroll
    for (int s = 0; s < KSPLIT; ++s)
        v += ws[(size_t)s * n_tokens * NE + (size_t)token * NE + lane];
    v *= INV_SCALE;                                   // undo 2^14 input scaling

    float m1 = v;
    #pragma unroll
    for (int off = 32; off >= 1; off >>= 1) m1 = fmaxf(m1, __shfl_xor(m1, off));
    unsigned long long b1 = __ballot(v == m1);        // lowest-index tie-break
    int i1 = __ffsll(b1) - 1;

    const float NINF = __int_as_float(0xff800000);
    float vx = (lane == i1) ? NINF : v;
    float m2 = vx;
    #pragma unroll
    for (int off = 32; off >= 1; off >>= 1) m2 = fmaxf(m2, __shfl_xor(m2, off));
    unsigned long long b2 = __ballot(vx == m2);
    int i2 = __ffsll(b2) - 1;

    float s = __expf(v - m1);
    #pragma unroll
    for (int off = 32; off >= 1; off >>= 1) s += __shfl_xor(s, off);

    if (lane == 0) {
        float inv = 1.0f / s;
        out[(size_t)token * 2 + 0] = inv;
        out[(size_t)token * 2 + 1] = __expf(m2 - m1) * inv;
        out[(size_t)n_tokens * 2 + (size_t)token * 2 + 0] = (float)i1;
        out[(size_t)n_tokens * 2 + (size_t)token * 2 + 1] = (float)i2;
    }
}

extern "C" void kernel_launch(void* const* d_in, const int* in_sizes, int n_in,
                              void* d_out, int out_size, void* d_ws, size_t ws_size,
                              hipStream_t stream)
{
    const float* x = (const float*)d_in[0];
    const float* W = (const float*)d_in[1];
    float* out = (float*)d_out;
    float* ws  = (float*)d_ws;

    const int n_tokens = in_sizes[0] / HS;            // 8192

    dim3 grid1(n_tokens / M_BLK, KSPLIT);             // (32, 8) = 256 blocks, 1/CU
    router_gemm<<<grid1, 512, 0, stream>>>(x, W, ws, n_tokens);

    dim3 grid2((n_tokens + 3) / 4);
    router_finish<<<grid2, 256, 0, stream>>>(ws, out, n_tokens);
}